// Round 10
// baseline (207.895 us; speedup 1.0000x reference)
//
#include <hip/hip_runtime.h>

// VQ-VAE vector quantizer, MI355X (gfx950).
// z: [B=32, C=256, H=32, W=32] fp32; emb: [K=1024, C=256] fp32.
// Outputs (flat f32): z_q [B,C,H,W] (8388608) | loss (1) | idx-as-float (32768).
//
// score = ||e||^2 - 2 z.e via ONE bf16 MFMA (A = bf16(-2z), B = bf16(e)),
// LDS-staged B chunks (R9). Pixels with top-2 gap < MARGIN go to npfix:
// R10 npfix = two-phase: Phase A finds candidate codes (coalesced fp32 FMA
// scan over transposed embT, window 1e-4 >> np-vs-exact differential 7e-5),
// Phase B runs the bit-exact numpy fp32 replica (pairwise sums + SSE einsum)
// only on those candidates (~1.3/pixel instead of 1024).

#define BB     32
#define CDIM   256
#define HW     1024
#define KK     1024
#define NPIX   (BB * HW)

#define MARGIN  2.5e-4f
#define WINCAND 1.0e-4f
#define CANDMAX 16
#define LISTCAP 16384
#define FPX     8

typedef __attribute__((ext_vector_type(8))) short bf16x8;
typedef __attribute__((ext_vector_type(4))) float f32x4;

__device__ __forceinline__ unsigned short bf16_rn(float f) {
    unsigned int u = __float_as_uint(f);
    unsigned int r = u + 0x7fffu + ((u >> 16) & 1u);   // RNE
    return (unsigned short)(r >> 16);
}
__device__ __forceinline__ f32x4 mfma16(bf16x8 a, bf16x8 b, f32x4 c) {
    return __builtin_amdgcn_mfma_f32_16x16x32_bf16(a, b, c, 0, 0, 0);
}

// ---------------------------------------------------- numpy pairwise replica
__device__ __forceinline__ float pw128_sq(const float* a) {
#pragma clang fp contract(off)
    float4 u = *(const float4*)(a);
    float4 v = *(const float4*)(a + 4);
    float r0 = u.x * u.x, r1 = u.y * u.y, r2 = u.z * u.z, r3 = u.w * u.w;
    float r4 = v.x * v.x, r5 = v.y * v.y, r6 = v.z * v.z, r7 = v.w * v.w;
    for (int i = 8; i < 128; i += 8) {
        float4 p = *(const float4*)(a + i);
        float4 q = *(const float4*)(a + i + 4);
        float s0 = p.x * p.x; r0 = r0 + s0;
        float s1 = p.y * p.y; r1 = r1 + s1;
        float s2 = p.z * p.z; r2 = r2 + s2;
        float s3 = p.w * p.w; r3 = r3 + s3;
        float s4 = q.x * q.x; r4 = r4 + s4;
        float s5 = q.y * q.y; r5 = r5 + s5;
        float s6 = q.z * q.z; r6 = r6 + s6;
        float s7 = q.w * q.w; r7 = r7 + s7;
    }
    return ((r0 + r1) + (r2 + r3)) + ((r4 + r5) + (r6 + r7));
}

// np einsum SSE replica: 4 lane accumulators, (l0+l1)+(l2+l3); then
// d = fl(fl(znp+en) - fl(2*dot)).
__device__ __forceinline__ float np_d_one(const float* __restrict__ er,
                                          const float* zr,   // LDS row
                                          float znp_v, float en) {
#pragma clang fp contract(off)
    float l0 = 0.f, l1 = 0.f, l2 = 0.f, l3 = 0.f;
    for (int m = 0; m < 64; ++m) {
        const float4 e4 = *(const float4*)(er + 4 * m);
        const float4 z4 = *(const float4*)(zr + 4 * m);
        float p0 = e4.x * z4.x; l0 = l0 + p0;
        float p1 = e4.y * z4.y; l1 = l1 + p1;
        float p2 = e4.z * z4.z; l2 = l2 + p2;
        float p3 = e4.w * z4.w; l3 = l3 + p3;
    }
    float dot = (l0 + l1) + (l2 + l3);
    float S   = znp_v + en;
    float tw  = 2.0f * dot;
    return S - tw;
}

// ------------------------------------- e-norms (numpy-bit-exact) + cnt reset
__global__ void enorm_np_kernel(const float* __restrict__ emb,
                                float* __restrict__ enorm,
                                int* __restrict__ cnt) {
    if (blockIdx.x == 0 && threadIdx.x == 0) cnt[0] = 0;
    const int k = blockIdx.x * blockDim.x + threadIdx.x;
    const float* e = emb + (size_t)k * CDIM;
    float s;
    {
#pragma clang fp contract(off)
        float L = pw128_sq(e);
        float R = pw128_sq(e + 128);
        s = L + R;
    }
    enorm[k] = s;
}

// ------------- emb -> bf16 chunk-fragment order + f32 transpose embT[c][k]
// chunk (kt,ks) = 256 codes x 32 c = 16 KB, fragments linear inside:
// off = ((kt*8+ks)*16 + k16)*512 + (lk*16+li)*8 + cj
__global__ void embcvt_kernel(const float* __restrict__ emb,
                              unsigned short* __restrict__ ehi,
                              float* __restrict__ embT) {
    const int i = blockIdx.x * 256 + threadIdx.x;   // 65536 float4s
    const int k = i >> 6;
    const int c = (i & 63) * 4;
    const float4 v = ((const float4*)emb)[i];
    ushort4 hv;
    hv.x = bf16_rn(v.x); hv.y = bf16_rn(v.y);
    hv.z = bf16_rn(v.z); hv.w = bf16_rn(v.w);
    const int kt = k >> 8, k16 = (k >> 4) & 15, li = k & 15;
    const int ks = c >> 5, lk = (c >> 3) & 3, cj = c & 7;
    const int off = (((kt * 8 + ks) * 16 + k16) << 9) + (lk * 16 + li) * 8 + cj;
    *(ushort4*)(ehi + off) = hv;
    embT[(c + 0) * KK + k] = v.x;
    embT[(c + 1) * KK + k] = v.y;
    embT[(c + 2) * KK + k] = v.z;
    embT[(c + 3) * KK + k] = v.w;
}

// ---------------------------------------------------------- MFMA argmin
__global__ __launch_bounds__(256, 2)
void argmin_mfma_kernel(const float* __restrict__ z,
                        const unsigned short* __restrict__ ehi,
                        const float* __restrict__ enorm,
                        int* __restrict__ idx_i, float* __restrict__ idx_f,
                        int* __restrict__ cnt, int* __restrict__ list) {
    __shared__ __align__(16) unsigned short zhi[64][272];
    __shared__ __align__(16) unsigned short blds[2][8192];   // 2 x 16 KB

    const int t    = threadIdx.x;
    const int px0  = blockIdx.x * 64;
    const int b    = px0 >> 10;
    const int hw0  = px0 & 1023;
    const int wn   = t >> 6;
    const int lane = t & 63;
    const int li   = lane & 15;
    const int lk   = lane >> 4;

    auto stage = [&](int ch, int buf) {
#pragma unroll
        for (int p = 0; p < 4; ++p) {
            const int part = wn * 4 + p;                    // 1 KB per part
            const unsigned short* gsl = ehi + (size_t)ch * 8192 + part * 512 + lane * 8;
            unsigned short* ldst = &blds[buf][part * 512];
            __builtin_amdgcn_global_load_lds(
                (const __attribute__((address_space(1))) unsigned int*)(const void*)gsl,
                (__attribute__((address_space(3))) unsigned int*)(void*)ldst,
                16, 0, 0);
        }
    };

#pragma unroll
    for (int it = 0; it < 16; ++it) {
        const int c     = it * 16 + (t >> 4);
        const int chunk = t & 15;
        const f32x4 v = __builtin_nontemporal_load(
            (const f32x4*)(z + ((size_t)(b * 256 + c)) * 1024 + hw0 + chunk * 4));
#pragma unroll
        for (int i = 0; i < 4; ++i) {
            const int ie = (i + chunk) & 3;
            const int px = chunk * 4 + ie;
            zhi[px][c] = bf16_rn(-2.0f * v[ie]);
        }
    }
    stage(0, 0);
    __syncthreads();

    float sb[4], sb2[4];
    int   si[4];
#pragma unroll
    for (int r = 0; r < 4; ++r) { sb[r] = 3.4e38f; sb2[r] = 3.4e38f; si[r] = 0; }

    f32x4 acc[16];

    for (int ch = 0; ch < 32; ++ch) {        // chunk = kt*8 + ks
        const int kt = ch >> 3;
        const int ks = ch & 7;
        const int buf = ch & 1;

        if (ks == 0) {
#pragma unroll
            for (int ni = 0; ni < 16; ++ni) {
                const float en = enorm[kt * 256 + ni * 16 + li];
                acc[ni][0] = en; acc[ni][1] = en; acc[ni][2] = en; acc[ni][3] = en;
            }
        }

        if (ch < 31) stage(ch + 1, buf ^ 1);

        const bf16x8 A = *(const bf16x8*)&zhi[wn * 16 + li][lk * 8 + ks * 32];
#pragma unroll
        for (int ni = 0; ni < 16; ++ni) {
            const bf16x8 Bf = *(const bf16x8*)&blds[buf][ni * 512 + lane * 8];
            acc[ni] = mfma16(A, Bf, acc[ni]);
        }

        if (ks == 7) {
#pragma unroll
            for (int ni = 0; ni < 16; ++ni) {
                const int k = kt * 256 + ni * 16 + li;
#pragma unroll
                for (int r = 0; r < 4; ++r) {
                    const float v = acc[ni][r];
                    if (v < sb[r]) {
                        sb2[r] = sb[r]; sb[r] = v; si[r] = k;
                    } else {
                        sb2[r] = fminf(sb2[r], v);
                    }
                }
            }
        }
        __syncthreads();
    }

#pragma unroll
    for (int m = 1; m < 16; m <<= 1) {
#pragma unroll
        for (int r = 0; r < 4; ++r) {
            const float ob  = __shfl_xor(sb[r], m, 64);
            const float ob2 = __shfl_xor(sb2[r], m, 64);
            const int   oi  = __shfl_xor(si[r], m, 64);
            const bool take = (ob < sb[r]) || (ob == sb[r] && oi < si[r]);
            const float mx  = take ? sb[r] : ob;
            sb2[r] = fminf(fminf(sb2[r], ob2), mx);
            if (take) { sb[r] = ob; si[r] = oi; }
        }
    }
    if (li == 0) {
#pragma unroll
        for (int r = 0; r < 4; ++r) {
            const int n = px0 + wn * 16 + lk * 4 + r;
            idx_i[n] = si[r];
            idx_f[n] = (float)si[r];
            if (sb2[r] - sb[r] < MARGIN) {
                const int slot = atomicAdd(cnt, 1);
                if (slot < LISTCAP) list[slot] = n;
            }
        }
    }
}

// ---------------- npfix v2: candidate scan (fast) + np-exact on candidates
__global__ __launch_bounds__(256)
void npfix_kernel(const float* __restrict__ z, const float* __restrict__ emb,
                  const float* __restrict__ embT,
                  const float* __restrict__ enorm_np,
                  const int* __restrict__ cnt, const int* __restrict__ list,
                  int* __restrict__ idx_i, float* __restrict__ idx_f) {
    __shared__ __align__(16) float zrow[FPX][CDIM];   // [px][c]
    __shared__ __align__(16) float zT[CDIM][FPX];     // [c][px]
    __shared__ float znp[FPX];
    __shared__ int   pxn[FPX];
    __shared__ float wmin[4][FPX];
    __shared__ float vminS[FPX];
    __shared__ int   candN[FPX];
    __shared__ int   candK[FPX][CANDMAX];
    __shared__ float candD[FPX][CANDMAX];

    const int t    = threadIdx.x;
    const int lane = t & 63;
    const int wv   = t >> 6;
    const int nflag = min(cnt[0], LISTCAP);

    for (int base = blockIdx.x * FPX; base < nflag; base += gridDim.x * FPX) {
        const int npx = min(FPX, nflag - base);
        if (t < FPX) pxn[t] = list[base + (t < npx ? t : npx - 1)];
        __syncthreads();
#pragma unroll
        for (int px = 0; px < FPX; ++px) {
            const int n = pxn[px];
            const float v = z[(size_t)(n >> 10) * (CDIM * HW) + (size_t)t * HW + (n & 1023)];
            zrow[px][t] = v;
            zT[t][px]   = v;
        }
        __syncthreads();
        if (t < FPX) {
#pragma clang fp contract(off)
            float L = pw128_sq(&zrow[t][0]);
            float R = pw128_sq(&zrow[t][128]);
            znp[t] = L + R;
            candN[t] = 0;
        }
        __syncthreads();

        // ---- Phase A: v' = en - 2*z.e for all k, fp32 FMA, coalesced embT
        float myv[4][FPX];
        float mymin[FPX];
#pragma unroll
        for (int p = 0; p < FPX; ++p) mymin[p] = 3.4e38f;

#pragma unroll
        for (int kj = 0; kj < 4; ++kj) {
            const int k = t + kj * 256;
            float l[FPX];
#pragma unroll
            for (int p = 0; p < FPX; ++p) l[p] = 0.f;
#pragma unroll 4
            for (int c = 0; c < CDIM; ++c) {
                const float e = embT[c * KK + k];
                const f32x4 za = *(const f32x4*)&zT[c][0];
                const f32x4 zb = *(const f32x4*)&zT[c][4];
                l[0] = fmaf(e, za[0], l[0]);
                l[1] = fmaf(e, za[1], l[1]);
                l[2] = fmaf(e, za[2], l[2]);
                l[3] = fmaf(e, za[3], l[3]);
                l[4] = fmaf(e, zb[0], l[4]);
                l[5] = fmaf(e, zb[1], l[5]);
                l[6] = fmaf(e, zb[2], l[6]);
                l[7] = fmaf(e, zb[3], l[7]);
            }
            const float en = enorm_np[k];
#pragma unroll
            for (int p = 0; p < FPX; ++p) {
                const float v = fmaf(-2.f, l[p], en);
                myv[kj][p] = v;
                mymin[p] = fminf(mymin[p], v);
            }
        }
        // wave-level min, then cross-wave
#pragma unroll
        for (int m = 1; m < 64; m <<= 1)
#pragma unroll
            for (int p = 0; p < FPX; ++p)
                mymin[p] = fminf(mymin[p], __shfl_xor(mymin[p], m, 64));
        if (lane == 0)
#pragma unroll
            for (int p = 0; p < FPX; ++p) wmin[wv][p] = mymin[p];
        __syncthreads();
        if (t < FPX)
            vminS[t] = fminf(fminf(wmin[0][t], wmin[1][t]),
                             fminf(wmin[2][t], wmin[3][t]));
        __syncthreads();

        // collect candidates within WINCAND of the minimum
#pragma unroll
        for (int kj = 0; kj < 4; ++kj)
#pragma unroll
            for (int p = 0; p < FPX; ++p) {
                if (myv[kj][p] <= vminS[p] + WINCAND) {
                    const int slot = atomicAdd(&candN[p], 1);
                    if (slot < CANDMAX) candK[p][slot] = t + kj * 256;
                }
            }
        __syncthreads();

        // ---- Phase B: np-exact d for each candidate
        if (t < FPX * CANDMAX) {
            const int p = t >> 4;
            const int j = t & (CANDMAX - 1);
            const int nc = min(candN[p], CANDMAX);
            if (j < nc) {
                const int k = candK[p][j];
                candD[p][j] = np_d_one(emb + (size_t)k * CDIM, &zrow[p][0],
                                       znp[p], enorm_np[k]);
            }
        }
        __syncthreads();
        if (t < npx) {
            const int p = t;
            const int nc = min(candN[p], CANDMAX);
            float bd = 3.4e38f; int bk = 0x7fffffff;
            for (int j = 0; j < nc; ++j) {
                const float d = candD[p][j];
                const int   k = candK[p][j];
                if (d < bd || (d == bd && k < bk)) { bd = d; bk = k; }
            }
            const int n = pxn[p];
            idx_i[n] = bk;
            idx_f[n] = (float)bk;
        }
        __syncthreads();
    }
}

// ---------------------------------------------------------------- z_q + loss
__global__ __launch_bounds__(256)
void zq_loss_kernel(const float* __restrict__ z, const float* __restrict__ emb,
                    const int* __restrict__ idx_i, float* __restrict__ zq,
                    double* __restrict__ lpart) {
    const int blk = blockIdx.x;
    const int b   = blk >> 3;
    const int cch = blk & 7;
    const int t   = threadIdx.x;
    const int hw  = t * 4;
    const int n0  = b * HW + hw;

    const float* e0 = emb + (size_t)idx_i[n0 + 0] * CDIM + cch * 32;
    const float* e1 = emb + (size_t)idx_i[n0 + 1] * CDIM + cch * 32;
    const float* e2 = emb + (size_t)idx_i[n0 + 2] * CDIM + cch * 32;
    const float* e3 = emb + (size_t)idx_i[n0 + 3] * CDIM + cch * 32;

    const size_t base = ((size_t)b * CDIM + cch * 32) * HW + hw;
    const float* zb = z + base;
    float*       ob = zq + base;

    float ls = 0.f;
#pragma unroll
    for (int c4 = 0; c4 < 8; ++c4) {
        const float4 a0 = *(const float4*)(e0 + 4 * c4);
        const float4 a1 = *(const float4*)(e1 + 4 * c4);
        const float4 a2 = *(const float4*)(e2 + 4 * c4);
        const float4 a3 = *(const float4*)(e3 + 4 * c4);
        const float av0[4] = {a0.x, a0.y, a0.z, a0.w};
        const float av1[4] = {a1.x, a1.y, a1.z, a1.w};
        const float av2[4] = {a2.x, a2.y, a2.z, a2.w};
        const float av3[4] = {a3.x, a3.y, a3.z, a3.w};
#pragma unroll
        for (int cj = 0; cj < 4; ++cj) {
            const size_t off = (size_t)(c4 * 4 + cj) * HW;
            const f32x4 zv = __builtin_nontemporal_load((const f32x4*)(zb + off));
            f32x4 o;
            o[0] = av0[cj]; o[1] = av1[cj]; o[2] = av2[cj]; o[3] = av3[cj];
            __builtin_nontemporal_store(o, (f32x4*)(ob + off));
            const float d0 = o[0] - zv[0], d1 = o[1] - zv[1];
            const float d2 = o[2] - zv[2], d3 = o[3] - zv[3];
            ls += d0 * d0 + d1 * d1 + d2 * d2 + d3 * d3;
        }
    }

    __shared__ float red[256];
    red[t] = ls;
    __syncthreads();
    if (t < 128) red[t] += red[t + 128];
    __syncthreads();
    if (t < 64) {
        float s = red[t] + red[t + 64];
#pragma unroll
        for (int off = 32; off > 0; off >>= 1) s += __shfl_down(s, off, 64);
        if (t == 0) lpart[blk] = (double)s;
    }
}

__global__ void loss_fin_kernel(const double* __restrict__ lpart,
                                float* __restrict__ loss_out) {
    const int t = threadIdx.x;
    double s = 0.0;
#pragma unroll
    for (int i = 0; i < 4; ++i) s += lpart[t * 4 + i];
#pragma unroll
    for (int off = 32; off > 0; off >>= 1) s += __shfl_down(s, off, 64);
    if (t == 0)
        loss_out[0] = (float)(0.25 * s / (double)((size_t)BB * CDIM * HW));
}

// ---------------------------------------------------------------- launch
extern "C" void kernel_launch(void* const* d_in, const int* in_sizes, int n_in,
                              void* d_out, int out_size, void* d_ws, size_t ws_size,
                              hipStream_t stream) {
    const float* z   = (const float*)d_in[0];
    const float* emb = (const float*)d_in[1];

    float* out  = (float*)d_out;
    float* zq   = out;
    float* loss = out + (size_t)BB * CDIM * HW;
    float* idxf = loss + 1;

    char* ws = (char*)d_ws;
    int*            idx_i = (int*)(ws);                      // 131072 B
    float*          enorm = (float*)(ws + 131072);           // 4096 B
    double*         lpart = (double*)(ws + 135168);          // 2048 B
    int*            cnt   = (int*)(ws + 137216);             // 256 B
    int*            list  = (int*)(ws + 137472);             // 65536 B
    unsigned short* ehi   = (unsigned short*)(ws + 203008);  // 524288 B
    float*          embT  = (float*)(ws + 727296);           // 1048576 B

    embcvt_kernel<<<256, 256, 0, stream>>>(emb, ehi, embT);
    enorm_np_kernel<<<KK / 256, 256, 0, stream>>>(emb, enorm, cnt);

    argmin_mfma_kernel<<<NPIX / 64, 256, 0, stream>>>(z, ehi, enorm,
                                                      idx_i, idxf, cnt, list);
    npfix_kernel<<<512, 256, 0, stream>>>(z, emb, embT, enorm, cnt, list,
                                          idx_i, idxf);

    zq_loss_kernel<<<BB * 8, 256, 0, stream>>>(z, emb, idx_i, zq, lpart);
    loss_fin_kernel<<<1, 64, 0, stream>>>(lpart, loss);
}

// Round 11
// 202.280 us; speedup vs baseline: 1.0278x; 1.0278x over previous
//
#include <hip/hip_runtime.h>

// VQ-VAE vector quantizer, MI355X (gfx950).
// z: [B=32, C=256, H=32, W=32] fp32; emb: [K=1024, C=256] fp32.
// Outputs (flat f32): z_q [B,C,H,W] (8388608) | loss (1) | idx-as-float (32768).
//
// score = ||e||^2 - 2 z.e via ONE bf16 MFMA (A = bf16(-2z), B = bf16(e)),
// LDS-staged B chunks (R9). Main kernel tracks TOP-3 (value,index):
//   gap3 < THR  -> list3: full bit-exact numpy-fp32 rescan   (~75 px)
//   gap2 < THR  -> list2: np-exact compare of {i1,i2} only   (~2200 px)
// np-winner is provably within 7e-5 (2x ulp(256)/2) of the exact min, and
// bf16 score noise sigma ~2.6e-5, so THR=5e-4 makes "np-winner outside
// bf16-top-2 while gap3>=THR" a >11-sigma event. R10 lesson: never rescan
// all 1024 codes in the fixup — reuse the main kernel's candidate info.

#define BB     32
#define CDIM   256
#define HW     1024
#define KK     1024
#define NPIX   (BB * HW)

#define THR     5.0e-4f
#define LISTCAP 16384
#define FPX     8
#define ENT2    32

typedef __attribute__((ext_vector_type(8))) short bf16x8;
typedef __attribute__((ext_vector_type(4))) float f32x4;

__device__ __forceinline__ unsigned short bf16_rn(float f) {
    unsigned int u = __float_as_uint(f);
    unsigned int r = u + 0x7fffu + ((u >> 16) & 1u);   // RNE
    return (unsigned short)(r >> 16);
}
__device__ __forceinline__ f32x4 mfma16(bf16x8 a, bf16x8 b, f32x4 c) {
    return __builtin_amdgcn_mfma_f32_16x16x32_bf16(a, b, c, 0, 0, 0);
}

// ---------------------------------------------------- numpy pairwise replica
__device__ __forceinline__ float pw128_sq(const float* a) {
#pragma clang fp contract(off)
    float4 u = *(const float4*)(a);
    float4 v = *(const float4*)(a + 4);
    float r0 = u.x * u.x, r1 = u.y * u.y, r2 = u.z * u.z, r3 = u.w * u.w;
    float r4 = v.x * v.x, r5 = v.y * v.y, r6 = v.z * v.z, r7 = v.w * v.w;
    for (int i = 8; i < 128; i += 8) {
        float4 p = *(const float4*)(a + i);
        float4 q = *(const float4*)(a + i + 4);
        float s0 = p.x * p.x; r0 = r0 + s0;
        float s1 = p.y * p.y; r1 = r1 + s1;
        float s2 = p.z * p.z; r2 = r2 + s2;
        float s3 = p.w * p.w; r3 = r3 + s3;
        float s4 = q.x * q.x; r4 = r4 + s4;
        float s5 = q.y * q.y; r5 = r5 + s5;
        float s6 = q.z * q.z; r6 = r6 + s6;
        float s7 = q.w * q.w; r7 = r7 + s7;
    }
    return ((r0 + r1) + (r2 + r3)) + ((r4 + r5) + (r6 + r7));
}

// np einsum SSE replica + final d = fl(fl(znp+en) - fl(2*dot))
__device__ __forceinline__ float np_d_one(const float* __restrict__ er,
                                          const float* zr, float znp_v, float en) {
#pragma clang fp contract(off)
    float l0 = 0.f, l1 = 0.f, l2 = 0.f, l3 = 0.f;
    for (int m = 0; m < 64; ++m) {
        const float4 e4 = *(const float4*)(er + 4 * m);
        const float4 z4 = *(const float4*)(zr + 4 * m);
        float p0 = e4.x * z4.x; l0 = l0 + p0;
        float p1 = e4.y * z4.y; l1 = l1 + p1;
        float p2 = e4.z * z4.z; l2 = l2 + p2;
        float p3 = e4.w * z4.w; l3 = l3 + p3;
    }
    float dot = (l0 + l1) + (l2 + l3);
    float S   = znp_v + en;
    float tw  = 2.0f * dot;
    return S - tw;
}

// ------------------------------------- e-norms (numpy-bit-exact) + cnt reset
__global__ void enorm_np_kernel(const float* __restrict__ emb,
                                float* __restrict__ enorm,
                                int* __restrict__ cnt) {
    if (blockIdx.x == 0 && threadIdx.x == 0) { cnt[0] = 0; cnt[1] = 0; }
    const int k = blockIdx.x * blockDim.x + threadIdx.x;
    const float* e = emb + (size_t)k * CDIM;
    float s;
    {
#pragma clang fp contract(off)
        float L = pw128_sq(e);
        float R = pw128_sq(e + 128);
        s = L + R;
    }
    enorm[k] = s;
}

// ------------- emb -> bf16, chunk-contiguous fragment order
// off = ((kt*8+ks)*16 + k16)*512 + (lk*16+li)*8 + cj
__global__ void embcvt_kernel(const float* __restrict__ emb,
                              unsigned short* __restrict__ ehi) {
    const int i = blockIdx.x * 256 + threadIdx.x;   // 65536 float4s
    const int k = i >> 6;
    const int c = (i & 63) * 4;
    const float4 v = ((const float4*)emb)[i];
    ushort4 hv;
    hv.x = bf16_rn(v.x); hv.y = bf16_rn(v.y);
    hv.z = bf16_rn(v.z); hv.w = bf16_rn(v.w);
    const int kt = k >> 8, k16 = (k >> 4) & 15, li = k & 15;
    const int ks = c >> 5, lk = (c >> 3) & 3, cj = c & 7;
    const int off = (((kt * 8 + ks) * 16 + k16) << 9) + (lk * 16 + li) * 8 + cj;
    *(ushort4*)(ehi + off) = hv;
}

// ---------------------------------------------------------- MFMA argmin
__global__ __launch_bounds__(256, 2)
void argmin_mfma_kernel(const float* __restrict__ z,
                        const unsigned short* __restrict__ ehi,
                        const float* __restrict__ enorm,
                        int* __restrict__ idx_i, float* __restrict__ idx_f,
                        int* __restrict__ cnt, int* __restrict__ list2,
                        int* __restrict__ list3) {
    __shared__ __align__(16) unsigned short zhi[64][272];
    __shared__ __align__(16) unsigned short blds[2][8192];   // 2 x 16 KB

    const int t    = threadIdx.x;
    const int px0  = blockIdx.x * 64;
    const int b    = px0 >> 10;
    const int hw0  = px0 & 1023;
    const int wn   = t >> 6;
    const int lane = t & 63;
    const int li   = lane & 15;
    const int lk   = lane >> 4;

    auto stage = [&](int ch, int buf) {
#pragma unroll
        for (int p = 0; p < 4; ++p) {
            const int part = wn * 4 + p;                    // 1 KB per part
            const unsigned short* gsl = ehi + (size_t)ch * 8192 + part * 512 + lane * 8;
            unsigned short* ldst = &blds[buf][part * 512];
            __builtin_amdgcn_global_load_lds(
                (const __attribute__((address_space(1))) unsigned int*)(const void*)gsl,
                (__attribute__((address_space(3))) unsigned int*)(void*)ldst,
                16, 0, 0);
        }
    };

#pragma unroll
    for (int it = 0; it < 16; ++it) {
        const int c     = it * 16 + (t >> 4);
        const int chunk = t & 15;
        const f32x4 v = __builtin_nontemporal_load(
            (const f32x4*)(z + ((size_t)(b * 256 + c)) * 1024 + hw0 + chunk * 4));
#pragma unroll
        for (int i = 0; i < 4; ++i) {
            const int ie = (i + chunk) & 3;
            const int px = chunk * 4 + ie;
            zhi[px][c] = bf16_rn(-2.0f * v[ie]);
        }
    }
    stage(0, 0);
    __syncthreads();

    // top-3 per lane slot r (value + index), k ascending so < keeps first-min
    float v1[4], v2[4], v3[4];
    int   i1[4], i2[4], i3[4];
#pragma unroll
    for (int r = 0; r < 4; ++r) {
        v1[r] = 3.4e38f; v2[r] = 3.4e38f; v3[r] = 3.4e38f;
        i1[r] = 0; i2[r] = 0; i3[r] = 0;
    }

    f32x4 acc[16];

    for (int ch = 0; ch < 32; ++ch) {        // chunk = kt*8 + ks
        const int kt = ch >> 3;
        const int ks = ch & 7;
        const int buf = ch & 1;

        if (ks == 0) {
#pragma unroll
            for (int ni = 0; ni < 16; ++ni) {
                const float en = enorm[kt * 256 + ni * 16 + li];
                acc[ni][0] = en; acc[ni][1] = en; acc[ni][2] = en; acc[ni][3] = en;
            }
        }

        if (ch < 31) stage(ch + 1, buf ^ 1);

        const bf16x8 A = *(const bf16x8*)&zhi[wn * 16 + li][lk * 8 + ks * 32];
#pragma unroll
        for (int ni = 0; ni < 16; ++ni) {
            const bf16x8 Bf = *(const bf16x8*)&blds[buf][ni * 512 + lane * 8];
            acc[ni] = mfma16(A, Bf, acc[ni]);
        }

        if (ks == 7) {
#pragma unroll
            for (int ni = 0; ni < 16; ++ni) {
                const int k = kt * 256 + ni * 16 + li;
#pragma unroll
                for (int r = 0; r < 4; ++r) {
                    const float v = acc[ni][r];
                    if (v < v1[r]) {
                        v3[r] = v2[r]; i3[r] = i2[r];
                        v2[r] = v1[r]; i2[r] = i1[r];
                        v1[r] = v;     i1[r] = k;
                    } else if (v < v2[r]) {
                        v3[r] = v2[r]; i3[r] = i2[r];
                        v2[r] = v;     i2[r] = k;
                    } else if (v < v3[r]) {
                        v3[r] = v;     i3[r] = k;
                    }
                }
            }
        }
        __syncthreads();
    }

    // dump per-lane top-3 into LDS (reuse blds) and serial-merge per pixel
    float* cv = (float*)&blds[0][0];                 // 1024 slots x 3 vals
    int*   ci = (int*)((char*)&blds[0][0] + 12288);  // 1024 slots x 3 idx
#pragma unroll
    for (int r = 0; r < 4; ++r) {
        const int slot = (((wn * 16 + li) * 4 + lk) * 4 + r) * 3;
        cv[slot + 0] = v1[r]; ci[slot + 0] = i1[r];
        cv[slot + 1] = v2[r]; ci[slot + 1] = i2[r];
        cv[slot + 2] = v3[r]; ci[slot + 2] = i3[r];
    }
    __syncthreads();
    if (t < 64) {
        const int rwn = t >> 4, rlk = (t >> 2) & 3, rr = t & 3;
        float V1 = 3.4e38f, V2 = 3.4e38f, V3 = 3.4e38f;
        int   I1 = 0x7fffffff, I2 = 0x7fffffff, I3 = 0x7fffffff;
#pragma unroll
        for (int l2 = 0; l2 < 16; ++l2) {
            const int slot = (((rwn * 16 + l2) * 4 + rlk) * 4 + rr) * 3;
#pragma unroll
            for (int j = 0; j < 3; ++j) {
                const float v = cv[slot + j];
                const int   k = ci[slot + j];
                if (v < V1 || (v == V1 && k < I1)) {
                    V3 = V2; I3 = I2; V2 = V1; I2 = I1; V1 = v; I1 = k;
                } else if (v < V2 || (v == V2 && k < I2)) {
                    V3 = V2; I3 = I2; V2 = v; I2 = k;
                } else if (v < V3 || (v == V3 && k < I3)) {
                    V3 = v; I3 = k;
                }
            }
        }
        const int n = px0 + t;
        idx_i[n] = I1;
        idx_f[n] = (float)I1;
        if (V3 - V1 < THR) {                      // 3+ candidates: full rescan
            const int slot = atomicAdd(&cnt[1], 1);
            if (slot < LISTCAP) list3[slot] = n;
        } else if (V2 - V1 < THR) {               // exactly 2 candidates
            const int slot = atomicAdd(&cnt[0], 1);
            if (slot < LISTCAP) list2[slot] = n | (I2 << 17);
        }
    }
}

// ------------- npfix2: np-exact compare of the two candidates per pixel
__global__ __launch_bounds__(256)
void npfix2_kernel(const float* __restrict__ z, const float* __restrict__ emb,
                   const float* __restrict__ enorm_np,
                   const int* __restrict__ cnt, const int* __restrict__ list2,
                   int* __restrict__ idx_i, float* __restrict__ idx_f) {
    __shared__ __align__(16) float zrow[ENT2][CDIM];
    __shared__ float znp[ENT2];
    __shared__ int   entn[ENT2], entk2[ENT2];
    __shared__ float dd[ENT2][2];
    __shared__ int   kk[ENT2][2];
    const int t = threadIdx.x;
    const int nflag = min(cnt[0], LISTCAP);

    for (int base = blockIdx.x * ENT2; base < nflag; base += gridDim.x * ENT2) {
        const int nb = min(ENT2, nflag - base);
        if (t < ENT2) {
            const int e = list2[base + (t < nb ? t : nb - 1)];
            entn[t]  = e & 0x1FFFF;
            entk2[t] = e >> 17;
        }
        __syncthreads();
        {   // stage z rows: 8 threads per entry
            const int e = t >> 3, part = t & 7;
            const int n = entn[e];
            const float* zb = z + (size_t)(n >> 10) * (CDIM * HW) + (n & 1023);
#pragma unroll
            for (int q = 0; q < 32; ++q) {
                const int c = part * 32 + q;
                zrow[e][c] = zb[(size_t)c * HW];
            }
        }
        __syncthreads();
        if (t < ENT2) {
#pragma clang fp contract(off)
            float L = pw128_sq(&zrow[t][0]);
            float R = pw128_sq(&zrow[t][128]);
            znp[t] = L + R;
        }
        __syncthreads();
        if (t < ENT2 * 2) {
            const int e = t >> 1, cnd = t & 1;
            const int k = cnd ? entk2[e] : idx_i[entn[e]];
            dd[e][cnd] = np_d_one(emb + (size_t)k * CDIM, &zrow[e][0],
                                  znp[e], enorm_np[k]);
            kk[e][cnd] = k;
        }
        __syncthreads();
        if (t < nb) {
            const float d0 = dd[t][0], d1 = dd[t][1];
            const int   k0 = kk[t][0], k1 = kk[t][1];
            const bool take1 = (d1 < d0) || (d1 == d0 && k1 < k0);
            const int bk = take1 ? k1 : k0;
            const int n = entn[t];
            idx_i[n] = bk;
            idx_f[n] = (float)bk;
        }
        __syncthreads();
    }
}

// ------------- npfix3: full bit-exact numpy rescan (rare 3+-cand pixels)
__global__ __launch_bounds__(256)
void npfix3_kernel(const float* __restrict__ z, const float* __restrict__ emb,
                   const float* __restrict__ enorm_np,
                   const int* __restrict__ cnt, const int* __restrict__ list3,
                   int* __restrict__ idx_i, float* __restrict__ idx_f) {
    __shared__ __align__(16) float zrow[FPX][CDIM];
    __shared__ float znp[FPX];
    __shared__ int   pxn[FPX];
    __shared__ float redv[256];
    __shared__ int   redk[256];
    const int t = threadIdx.x;
    const int nflag = min(cnt[1], LISTCAP);

    for (int base = blockIdx.x * FPX; base < nflag; base += gridDim.x * FPX) {
        const int npx = min(FPX, nflag - base);
        if (t < FPX) pxn[t] = list3[base + (t < npx ? t : npx - 1)];
        __syncthreads();
#pragma unroll
        for (int px = 0; px < FPX; ++px) {
            const int n = pxn[px];
            zrow[px][t] = z[(size_t)(n >> 10) * (CDIM * HW) + (size_t)t * HW + (n & 1023)];
        }
        __syncthreads();
        if (t < FPX) {
#pragma clang fp contract(off)
            float L = pw128_sq(&zrow[t][0]);
            float R = pw128_sq(&zrow[t][128]);
            znp[t] = L + R;
        }
        __syncthreads();

        float bv[FPX]; int bki[FPX];
#pragma unroll
        for (int px = 0; px < FPX; ++px) { bv[px] = 3.4e38f; bki[px] = 0; }

        for (int kj = 0; kj < 4; ++kj) {
            const int k = t + kj * 256;
            const float* er = emb + (size_t)k * CDIM;
            float l[FPX][4];
#pragma unroll
            for (int px = 0; px < FPX; ++px)
#pragma unroll
                for (int j = 0; j < 4; ++j) l[px][j] = 0.f;
            {
#pragma clang fp contract(off)
                for (int m = 0; m < 64; ++m) {
                    const float4 e4 = *(const float4*)(er + 4 * m);
#pragma unroll
                    for (int px = 0; px < FPX; ++px) {
                        const float4 z4 = *(const float4*)(&zrow[px][4 * m]);
                        float p0 = e4.x * z4.x; l[px][0] = l[px][0] + p0;
                        float p1 = e4.y * z4.y; l[px][1] = l[px][1] + p1;
                        float p2 = e4.z * z4.z; l[px][2] = l[px][2] + p2;
                        float p3 = e4.w * z4.w; l[px][3] = l[px][3] + p3;
                    }
                }
#pragma unroll
                for (int px = 0; px < FPX; ++px) {
                    float dot = (l[px][0] + l[px][1]) + (l[px][2] + l[px][3]);
                    float S   = znp[px] + enorm_np[k];
                    float tw  = 2.0f * dot;
                    float d   = S - tw;
                    if (d < bv[px]) { bv[px] = d; bki[px] = k; }
                }
            }
        }
        for (int px = 0; px < FPX; ++px) {
            __syncthreads();
            redv[t] = bv[px]; redk[t] = bki[px];
            __syncthreads();
            for (int s = 128; s > 0; s >>= 1) {
                if (t < s) {
                    const float v2 = redv[t + s];
                    const int   k2 = redk[t + s];
                    if (v2 < redv[t] || (v2 == redv[t] && k2 < redk[t])) {
                        redv[t] = v2; redk[t] = k2;
                    }
                }
                __syncthreads();
            }
            if (t == 0 && px < npx) {
                const int n = pxn[px];
                idx_i[n] = redk[0];
                idx_f[n] = (float)redk[0];
            }
        }
        __syncthreads();
    }
}

// ---------------------------------------------------------------- z_q + loss
__global__ __launch_bounds__(256)
void zq_loss_kernel(const float* __restrict__ z, const float* __restrict__ emb,
                    const int* __restrict__ idx_i, float* __restrict__ zq,
                    double* __restrict__ lpart) {
    const int blk = blockIdx.x;
    const int b   = blk >> 3;
    const int cch = blk & 7;
    const int t   = threadIdx.x;
    const int hw  = t * 4;
    const int n0  = b * HW + hw;

    const float* e0 = emb + (size_t)idx_i[n0 + 0] * CDIM + cch * 32;
    const float* e1 = emb + (size_t)idx_i[n0 + 1] * CDIM + cch * 32;
    const float* e2 = emb + (size_t)idx_i[n0 + 2] * CDIM + cch * 32;
    const float* e3 = emb + (size_t)idx_i[n0 + 3] * CDIM + cch * 32;

    const size_t base = ((size_t)b * CDIM + cch * 32) * HW + hw;
    const float* zb = z + base;
    float*       ob = zq + base;

    float ls = 0.f;
#pragma unroll
    for (int c4 = 0; c4 < 8; ++c4) {
        const float4 a0 = *(const float4*)(e0 + 4 * c4);
        const float4 a1 = *(const float4*)(e1 + 4 * c4);
        const float4 a2 = *(const float4*)(e2 + 4 * c4);
        const float4 a3 = *(const float4*)(e3 + 4 * c4);
        const float av0[4] = {a0.x, a0.y, a0.z, a0.w};
        const float av1[4] = {a1.x, a1.y, a1.z, a1.w};
        const float av2[4] = {a2.x, a2.y, a2.z, a2.w};
        const float av3[4] = {a3.x, a3.y, a3.z, a3.w};
#pragma unroll
        for (int cj = 0; cj < 4; ++cj) {
            const size_t off = (size_t)(c4 * 4 + cj) * HW;
            const f32x4 zv = __builtin_nontemporal_load((const f32x4*)(zb + off));
            f32x4 o;
            o[0] = av0[cj]; o[1] = av1[cj]; o[2] = av2[cj]; o[3] = av3[cj];
            __builtin_nontemporal_store(o, (f32x4*)(ob + off));
            const float d0 = o[0] - zv[0], d1 = o[1] - zv[1];
            const float d2 = o[2] - zv[2], d3 = o[3] - zv[3];
            ls += d0 * d0 + d1 * d1 + d2 * d2 + d3 * d3;
        }
    }

    __shared__ float red[256];
    red[t] = ls;
    __syncthreads();
    if (t < 128) red[t] += red[t + 128];
    __syncthreads();
    if (t < 64) {
        float s = red[t] + red[t + 64];
#pragma unroll
        for (int off = 32; off > 0; off >>= 1) s += __shfl_down(s, off, 64);
        if (t == 0) lpart[blk] = (double)s;
    }
}

__global__ void loss_fin_kernel(const double* __restrict__ lpart,
                                float* __restrict__ loss_out) {
    const int t = threadIdx.x;
    double s = 0.0;
#pragma unroll
    for (int i = 0; i < 4; ++i) s += lpart[t * 4 + i];
#pragma unroll
    for (int off = 32; off > 0; off >>= 1) s += __shfl_down(s, off, 64);
    if (t == 0)
        loss_out[0] = (float)(0.25 * s / (double)((size_t)BB * CDIM * HW));
}

// ---------------------------------------------------------------- launch
extern "C" void kernel_launch(void* const* d_in, const int* in_sizes, int n_in,
                              void* d_out, int out_size, void* d_ws, size_t ws_size,
                              hipStream_t stream) {
    const float* z   = (const float*)d_in[0];
    const float* emb = (const float*)d_in[1];

    float* out  = (float*)d_out;
    float* zq   = out;
    float* loss = out + (size_t)BB * CDIM * HW;
    float* idxf = loss + 1;

    char* ws = (char*)d_ws;
    int*            idx_i = (int*)(ws);                      // 131072 B
    float*          enorm = (float*)(ws + 131072);           // 4096 B
    double*         lpart = (double*)(ws + 135168);          // 2048 B
    int*            cnt   = (int*)(ws + 137216);             // 256 B
    int*            list2 = (int*)(ws + 137472);             // 65536 B
    int*            list3 = (int*)(ws + 203008);             // 65536 B
    unsigned short* ehi   = (unsigned short*)(ws + 268544);  // 524288 B

    embcvt_kernel<<<256, 256, 0, stream>>>(emb, ehi);
    enorm_np_kernel<<<KK / 256, 256, 0, stream>>>(emb, enorm, cnt);

    argmin_mfma_kernel<<<NPIX / 64, 256, 0, stream>>>(z, ehi, enorm,
                                                      idx_i, idxf, cnt,
                                                      list2, list3);
    npfix2_kernel<<<256, 256, 0, stream>>>(z, emb, enorm, cnt, list2,
                                           idx_i, idxf);
    npfix3_kernel<<<128, 256, 0, stream>>>(z, emb, enorm, cnt, list3,
                                           idx_i, idxf);

    zq_loss_kernel<<<BB * 8, 256, 0, stream>>>(z, emb, idx_i, zq, lpart);
    loss_fin_kernel<<<1, 64, 0, stream>>>(lpart, loss);
}

// Round 12
// 192.435 us; speedup vs baseline: 1.0803x; 1.0512x over previous
//
#include <hip/hip_runtime.h>

// VQ-VAE vector quantizer, MI355X (gfx950).
// z: [B=32, C=256, H=32, W=32] fp32; emb: [K=1024, C=256] fp32.
// Outputs (flat f32): z_q [B,C,H,W] (8388608) | loss (1) | idx-as-float (32768).
//
// score = ||e||^2 - 2 z.e via ONE bf16 MFMA (A = bf16(-2z), B = bf16(e)),
// LDS-staged B chunks (R9 structure). R12: scores tracked as packed u64
// keys (ord(value)<<32 | k) -> branchless per-lane top-2, shuffle merge
// network reconstructs per-pixel top-3 (exact unless top-3 codes collide
// mod 16: P~0.4%, and only ~1px/run is in the 3-way danger zone).
//   gap3 < THR -> list3: full bit-exact numpy-fp32 rescan (~tens of px)
//   gap2 < THR -> list2: np-exact compare of {i1,i2} only  (~1100 px)
// np-winner is within 7e-5 (2x ulp(256)/2) of the exact min; bf16 noise
// sigma ~2.6e-5; THR=2.5e-4 margins proven across R3-R9 runs.
// R11 lesson: branchy 3-deep inserts in the hot loop cost +85us of VALU.

#define BB     32
#define CDIM   256
#define HW     1024
#define KK     1024
#define NPIX   (BB * HW)

#define THR     2.5e-4f
#define LISTCAP 16384
#define FPX     8
#define ENT2    32

typedef __attribute__((ext_vector_type(8))) short bf16x8;
typedef __attribute__((ext_vector_type(4))) float f32x4;
typedef unsigned long long u64;
typedef unsigned int u32;

__device__ __forceinline__ unsigned short bf16_rn(float f) {
    unsigned int u = __float_as_uint(f);
    unsigned int r = u + 0x7fffu + ((u >> 16) & 1u);   // RNE
    return (unsigned short)(r >> 16);
}
__device__ __forceinline__ f32x4 mfma16(bf16x8 a, bf16x8 b, f32x4 c) {
    return __builtin_amdgcn_mfma_f32_16x16x32_bf16(a, b, c, 0, 0, 0);
}
// orderable-uint transform: a<b (float) <=> ord(a)<ord(b) (u32)
__device__ __forceinline__ u32 ordf(float v) {
    const u32 b = __float_as_uint(v);
    return b ^ ((u32)((int)b >> 31) | 0x80000000u);
}
__device__ __forceinline__ float unordf(u32 u) {
    const u32 b = (u & 0x80000000u) ? (u ^ 0x80000000u) : ~u;
    return __uint_as_float(b);
}
__device__ __forceinline__ u64 min64(u64 a, u64 b) { return a < b ? a : b; }
__device__ __forceinline__ u64 max64(u64 a, u64 b) { return a > b ? a : b; }

// ---------------------------------------------------- numpy pairwise replica
__device__ __forceinline__ float pw128_sq(const float* a) {
#pragma clang fp contract(off)
    float4 u = *(const float4*)(a);
    float4 v = *(const float4*)(a + 4);
    float r0 = u.x * u.x, r1 = u.y * u.y, r2 = u.z * u.z, r3 = u.w * u.w;
    float r4 = v.x * v.x, r5 = v.y * v.y, r6 = v.z * v.z, r7 = v.w * v.w;
    for (int i = 8; i < 128; i += 8) {
        float4 p = *(const float4*)(a + i);
        float4 q = *(const float4*)(a + i + 4);
        float s0 = p.x * p.x; r0 = r0 + s0;
        float s1 = p.y * p.y; r1 = r1 + s1;
        float s2 = p.z * p.z; r2 = r2 + s2;
        float s3 = p.w * p.w; r3 = r3 + s3;
        float s4 = q.x * q.x; r4 = r4 + s4;
        float s5 = q.y * q.y; r5 = r5 + s5;
        float s6 = q.z * q.z; r6 = r6 + s6;
        float s7 = q.w * q.w; r7 = r7 + s7;
    }
    return ((r0 + r1) + (r2 + r3)) + ((r4 + r5) + (r6 + r7));
}

// np einsum SSE replica + final d = fl(fl(znp+en) - fl(2*dot))
__device__ __forceinline__ float np_d_one(const float* __restrict__ er,
                                          const float* zr, float znp_v, float en) {
#pragma clang fp contract(off)
    float l0 = 0.f, l1 = 0.f, l2 = 0.f, l3 = 0.f;
    for (int m = 0; m < 64; ++m) {
        const float4 e4 = *(const float4*)(er + 4 * m);
        const float4 z4 = *(const float4*)(zr + 4 * m);
        float p0 = e4.x * z4.x; l0 = l0 + p0;
        float p1 = e4.y * z4.y; l1 = l1 + p1;
        float p2 = e4.z * z4.z; l2 = l2 + p2;
        float p3 = e4.w * z4.w; l3 = l3 + p3;
    }
    float dot = (l0 + l1) + (l2 + l3);
    float S   = znp_v + en;
    float tw  = 2.0f * dot;
    return S - tw;
}

// ------------------------------------- e-norms (numpy-bit-exact) + cnt reset
__global__ void enorm_np_kernel(const float* __restrict__ emb,
                                float* __restrict__ enorm,
                                int* __restrict__ cnt) {
    if (blockIdx.x == 0 && threadIdx.x == 0) { cnt[0] = 0; cnt[1] = 0; }
    const int k = blockIdx.x * blockDim.x + threadIdx.x;
    const float* e = emb + (size_t)k * CDIM;
    float s;
    {
#pragma clang fp contract(off)
        float L = pw128_sq(e);
        float R = pw128_sq(e + 128);
        s = L + R;
    }
    enorm[k] = s;
}

// ------------- emb -> bf16, chunk-contiguous fragment order
// off = ((kt*8+ks)*16 + k16)*512 + (lk*16+li)*8 + cj
__global__ void embcvt_kernel(const float* __restrict__ emb,
                              unsigned short* __restrict__ ehi) {
    const int i = blockIdx.x * 256 + threadIdx.x;   // 65536 float4s
    const int k = i >> 6;
    const int c = (i & 63) * 4;
    const float4 v = ((const float4*)emb)[i];
    ushort4 hv;
    hv.x = bf16_rn(v.x); hv.y = bf16_rn(v.y);
    hv.z = bf16_rn(v.z); hv.w = bf16_rn(v.w);
    const int kt = k >> 8, k16 = (k >> 4) & 15, li = k & 15;
    const int ks = c >> 5, lk = (c >> 3) & 3, cj = c & 7;
    const int off = (((kt * 8 + ks) * 16 + k16) << 9) + (lk * 16 + li) * 8 + cj;
    *(ushort4*)(ehi + off) = hv;
}

// ---------------------------------------------------------- MFMA argmin
__global__ __launch_bounds__(256, 2)
void argmin_mfma_kernel(const float* __restrict__ z,
                        const unsigned short* __restrict__ ehi,
                        const float* __restrict__ enorm,
                        int* __restrict__ idx_i, float* __restrict__ idx_f,
                        int* __restrict__ cnt, int* __restrict__ list2,
                        int* __restrict__ list3) {
    __shared__ __align__(16) unsigned short zhi[64][272];
    __shared__ __align__(16) unsigned short blds[2][8192];   // 2 x 16 KB

    const int t    = threadIdx.x;
    const int px0  = blockIdx.x * 64;
    const int b    = px0 >> 10;
    const int hw0  = px0 & 1023;
    const int wn   = t >> 6;
    const int lane = t & 63;
    const int li   = lane & 15;
    const int lk   = lane >> 4;

    auto stage = [&](int ch, int buf) {
#pragma unroll
        for (int p = 0; p < 4; ++p) {
            const int part = wn * 4 + p;                    // 1 KB per part
            const unsigned short* gsl = ehi + (size_t)ch * 8192 + part * 512 + lane * 8;
            unsigned short* ldst = &blds[buf][part * 512];
            __builtin_amdgcn_global_load_lds(
                (const __attribute__((address_space(1))) unsigned int*)(const void*)gsl,
                (__attribute__((address_space(3))) unsigned int*)(void*)ldst,
                16, 0, 0);
        }
    };

#pragma unroll
    for (int it = 0; it < 16; ++it) {
        const int c     = it * 16 + (t >> 4);
        const int chunk = t & 15;
        const f32x4 v = __builtin_nontemporal_load(
            (const f32x4*)(z + ((size_t)(b * 256 + c)) * 1024 + hw0 + chunk * 4));
#pragma unroll
        for (int i = 0; i < 4; ++i) {
            const int ie = (i + chunk) & 3;
            const int px = chunk * 4 + ie;
            zhi[px][c] = bf16_rn(-2.0f * v[ie]);
        }
    }
    stage(0, 0);
    __syncthreads();

    // per-lane top-2 as packed u64 keys (ord(v)<<32 | k); K3 filled by merge
    u64 K1[4], K2[4], K3[4];
#pragma unroll
    for (int r = 0; r < 4; ++r) { K1[r] = ~0ull; K2[r] = ~0ull; K3[r] = ~0ull; }

    f32x4 acc[16];

    for (int ch = 0; ch < 32; ++ch) {        // chunk = kt*8 + ks
        const int kt = ch >> 3;
        const int ks = ch & 7;
        const int buf = ch & 1;

        if (ks == 0) {
#pragma unroll
            for (int ni = 0; ni < 16; ++ni) {
                const float en = enorm[kt * 256 + ni * 16 + li];
                acc[ni][0] = en; acc[ni][1] = en; acc[ni][2] = en; acc[ni][3] = en;
            }
        }

        if (ch < 31) stage(ch + 1, buf ^ 1);

        const bf16x8 A = *(const bf16x8*)&zhi[wn * 16 + li][lk * 8 + ks * 32];
#pragma unroll
        for (int ni = 0; ni < 16; ++ni) {
            const bf16x8 Bf = *(const bf16x8*)&blds[buf][ni * 512 + lane * 8];
            acc[ni] = mfma16(A, Bf, acc[ni]);
        }

        if (ks == 7) {
#pragma unroll
            for (int ni = 0; ni < 16; ++ni) {
                const u32 k = (u32)(kt * 256 + ni * 16 + li);
#pragma unroll
                for (int r = 0; r < 4; ++r) {
                    const u64 key = ((u64)ordf(acc[ni][r]) << 32) | k;
                    const u64 mx  = max64(K1[r], key);
                    K1[r] = min64(K1[r], key);
                    K2[r] = min64(K2[r], mx);
                }
            }
        }
        __syncthreads();
    }

    // cross-lane merge over the 16 li lanes: 3-list merge network
#pragma unroll
    for (int m = 1; m < 16; m <<= 1) {
#pragma unroll
        for (int r = 0; r < 4; ++r) {
            const u64 b1 = __shfl_xor(K1[r], m, 64);
            const u64 b2 = __shfl_xor(K2[r], m, 64);
            const u64 b3 = __shfl_xor(K3[r], m, 64);
            const u64 m1 = min64(K1[r], b1), M1 = max64(K1[r], b1);
            const u64 m2 = min64(K2[r], b2), M2 = max64(K2[r], b2);
            K1[r] = m1;
            K2[r] = min64(M1, m2);
            K3[r] = min64(max64(M1, m2), min64(M2, min64(K3[r], b3)));
        }
    }
    if (li == 0) {
#pragma unroll
        for (int r = 0; r < 4; ++r) {
            const int n  = px0 + wn * 16 + lk * 4 + r;
            const int i1 = (int)(K1[r] & 0xffffffffu);
            const int i2 = (int)(K2[r] & 0xffffffffu);
            const float v1 = unordf((u32)(K1[r] >> 32));
            const float v2 = unordf((u32)(K2[r] >> 32));
            const float v3 = unordf((u32)(K3[r] >> 32));
            idx_i[n] = i1;
            idx_f[n] = (float)i1;
            if (v3 - v1 < THR) {                  // 3+ candidates: full rescan
                const int slot = atomicAdd(&cnt[1], 1);
                if (slot < LISTCAP) list3[slot] = n;
            } else if (v2 - v1 < THR) {           // exactly 2 candidates
                const int slot = atomicAdd(&cnt[0], 1);
                if (slot < LISTCAP) list2[slot] = n | (i2 << 17);
            }
        }
    }
}

// ------------- npfix2: np-exact compare of the two candidates per pixel
__global__ __launch_bounds__(256)
void npfix2_kernel(const float* __restrict__ z, const float* __restrict__ emb,
                   const float* __restrict__ enorm_np,
                   const int* __restrict__ cnt, const int* __restrict__ list2,
                   int* __restrict__ idx_i, float* __restrict__ idx_f) {
    __shared__ __align__(16) float zrow[ENT2][CDIM];
    __shared__ float znp[ENT2];
    __shared__ int   entn[ENT2], entk2[ENT2];
    __shared__ float dd[ENT2][2];
    __shared__ int   kk[ENT2][2];
    const int t = threadIdx.x;
    const int nflag = min(cnt[0], LISTCAP);

    for (int base = blockIdx.x * ENT2; base < nflag; base += gridDim.x * ENT2) {
        const int nb = min(ENT2, nflag - base);
        if (t < ENT2) {
            const int e = list2[base + (t < nb ? t : nb - 1)];
            entn[t]  = e & 0x1FFFF;
            entk2[t] = e >> 17;
        }
        __syncthreads();
        {   // stage z rows: 8 threads per entry
            const int e = t >> 3, part = t & 7;
            const int n = entn[e];
            const float* zb = z + (size_t)(n >> 10) * (CDIM * HW) + (n & 1023);
#pragma unroll
            for (int q = 0; q < 32; ++q) {
                const int c = part * 32 + q;
                zrow[e][c] = zb[(size_t)c * HW];
            }
        }
        __syncthreads();
        if (t < ENT2) {
#pragma clang fp contract(off)
            float L = pw128_sq(&zrow[t][0]);
            float R = pw128_sq(&zrow[t][128]);
            znp[t] = L + R;
        }
        __syncthreads();
        if (t < ENT2 * 2) {
            const int e = t >> 1, cnd = t & 1;
            const int k = cnd ? entk2[e] : idx_i[entn[e]];
            dd[e][cnd] = np_d_one(emb + (size_t)k * CDIM, &zrow[e][0],
                                  znp[e], enorm_np[k]);
            kk[e][cnd] = k;
        }
        __syncthreads();
        if (t < nb) {
            const float d0 = dd[t][0], d1 = dd[t][1];
            const int   k0 = kk[t][0], k1 = kk[t][1];
            const bool take1 = (d1 < d0) || (d1 == d0 && k1 < k0);
            const int bk = take1 ? k1 : k0;
            const int n = entn[t];
            idx_i[n] = bk;
            idx_f[n] = (float)bk;
        }
        __syncthreads();
    }
}

// ------------- npfix3: full bit-exact numpy rescan (rare 3+-cand pixels)
__global__ __launch_bounds__(256)
void npfix3_kernel(const float* __restrict__ z, const float* __restrict__ emb,
                   const float* __restrict__ enorm_np,
                   const int* __restrict__ cnt, const int* __restrict__ list3,
                   int* __restrict__ idx_i, float* __restrict__ idx_f) {
    __shared__ __align__(16) float zrow[FPX][CDIM];
    __shared__ float znp[FPX];
    __shared__ int   pxn[FPX];
    __shared__ float redv[256];
    __shared__ int   redk[256];
    const int t = threadIdx.x;
    const int nflag = min(cnt[1], LISTCAP);

    for (int base = blockIdx.x * FPX; base < nflag; base += gridDim.x * FPX) {
        const int npx = min(FPX, nflag - base);
        if (t < FPX) pxn[t] = list3[base + (t < npx ? t : npx - 1)];
        __syncthreads();
#pragma unroll
        for (int px = 0; px < FPX; ++px) {
            const int n = pxn[px];
            zrow[px][t] = z[(size_t)(n >> 10) * (CDIM * HW) + (size_t)t * HW + (n & 1023)];
        }
        __syncthreads();
        if (t < FPX) {
#pragma clang fp contract(off)
            float L = pw128_sq(&zrow[t][0]);
            float R = pw128_sq(&zrow[t][128]);
            znp[t] = L + R;
        }
        __syncthreads();

        float bv[FPX]; int bki[FPX];
#pragma unroll
        for (int px = 0; px < FPX; ++px) { bv[px] = 3.4e38f; bki[px] = 0; }

        for (int kj = 0; kj < 4; ++kj) {
            const int k = t + kj * 256;
            const float* er = emb + (size_t)k * CDIM;
            float l[FPX][4];
#pragma unroll
            for (int px = 0; px < FPX; ++px)
#pragma unroll
                for (int j = 0; j < 4; ++j) l[px][j] = 0.f;
            {
#pragma clang fp contract(off)
                for (int m = 0; m < 64; ++m) {
                    const float4 e4 = *(const float4*)(er + 4 * m);
#pragma unroll
                    for (int px = 0; px < FPX; ++px) {
                        const float4 z4 = *(const float4*)(&zrow[px][4 * m]);
                        float p0 = e4.x * z4.x; l[px][0] = l[px][0] + p0;
                        float p1 = e4.y * z4.y; l[px][1] = l[px][1] + p1;
                        float p2 = e4.z * z4.z; l[px][2] = l[px][2] + p2;
                        float p3 = e4.w * z4.w; l[px][3] = l[px][3] + p3;
                    }
                }
#pragma unroll
                for (int px = 0; px < FPX; ++px) {
                    float dot = (l[px][0] + l[px][1]) + (l[px][2] + l[px][3]);
                    float S   = znp[px] + enorm_np[k];
                    float tw  = 2.0f * dot;
                    float d   = S - tw;
                    if (d < bv[px]) { bv[px] = d; bki[px] = k; }
                }
            }
        }
        for (int px = 0; px < FPX; ++px) {
            __syncthreads();
            redv[t] = bv[px]; redk[t] = bki[px];
            __syncthreads();
            for (int s = 128; s > 0; s >>= 1) {
                if (t < s) {
                    const float v2 = redv[t + s];
                    const int   k2 = redk[t + s];
                    if (v2 < redv[t] || (v2 == redv[t] && k2 < redk[t])) {
                        redv[t] = v2; redk[t] = k2;
                    }
                }
                __syncthreads();
            }
            if (t == 0 && px < npx) {
                const int n = pxn[px];
                idx_i[n] = redk[0];
                idx_f[n] = (float)redk[0];
            }
        }
        __syncthreads();
    }
}

// ---------------------------------------------------------------- z_q + loss
__global__ __launch_bounds__(256)
void zq_loss_kernel(const float* __restrict__ z, const float* __restrict__ emb,
                    const int* __restrict__ idx_i, float* __restrict__ zq,
                    double* __restrict__ lpart) {
    const int blk = blockIdx.x;
    const int b   = blk >> 3;
    const int cch = blk & 7;
    const int t   = threadIdx.x;
    const int hw  = t * 4;
    const int n0  = b * HW + hw;

    const float* e0 = emb + (size_t)idx_i[n0 + 0] * CDIM + cch * 32;
    const float* e1 = emb + (size_t)idx_i[n0 + 1] * CDIM + cch * 32;
    const float* e2 = emb + (size_t)idx_i[n0 + 2] * CDIM + cch * 32;
    const float* e3 = emb + (size_t)idx_i[n0 + 3] * CDIM + cch * 32;

    const size_t base = ((size_t)b * CDIM + cch * 32) * HW + hw;
    const float* zb = z + base;
    float*       ob = zq + base;

    float ls = 0.f;
#pragma unroll
    for (int c4 = 0; c4 < 8; ++c4) {
        const float4 a0 = *(const float4*)(e0 + 4 * c4);
        const float4 a1 = *(const float4*)(e1 + 4 * c4);
        const float4 a2 = *(const float4*)(e2 + 4 * c4);
        const float4 a3 = *(const float4*)(e3 + 4 * c4);
        const float av0[4] = {a0.x, a0.y, a0.z, a0.w};
        const float av1[4] = {a1.x, a1.y, a1.z, a1.w};
        const float av2[4] = {a2.x, a2.y, a2.z, a2.w};
        const float av3[4] = {a3.x, a3.y, a3.z, a3.w};
#pragma unroll
        for (int cj = 0; cj < 4; ++cj) {
            const size_t off = (size_t)(c4 * 4 + cj) * HW;
            const f32x4 zv = __builtin_nontemporal_load((const f32x4*)(zb + off));
            f32x4 o;
            o[0] = av0[cj]; o[1] = av1[cj]; o[2] = av2[cj]; o[3] = av3[cj];
            __builtin_nontemporal_store(o, (f32x4*)(ob + off));
            const float d0 = o[0] - zv[0], d1 = o[1] - zv[1];
            const float d2 = o[2] - zv[2], d3 = o[3] - zv[3];
            ls += d0 * d0 + d1 * d1 + d2 * d2 + d3 * d3;
        }
    }

    __shared__ float red[256];
    red[t] = ls;
    __syncthreads();
    if (t < 128) red[t] += red[t + 128];
    __syncthreads();
    if (t < 64) {
        float s = red[t] + red[t + 64];
#pragma unroll
        for (int off = 32; off > 0; off >>= 1) s += __shfl_down(s, off, 64);
        if (t == 0) lpart[blk] = (double)s;
    }
}

__global__ void loss_fin_kernel(const double* __restrict__ lpart,
                                float* __restrict__ loss_out) {
    const int t = threadIdx.x;
    double s = 0.0;
#pragma unroll
    for (int i = 0; i < 4; ++i) s += lpart[t * 4 + i];
#pragma unroll
    for (int off = 32; off > 0; off >>= 1) s += __shfl_down(s, off, 64);
    if (t == 0)
        loss_out[0] = (float)(0.25 * s / (double)((size_t)BB * CDIM * HW));
}

// ---------------------------------------------------------------- launch
extern "C" void kernel_launch(void* const* d_in, const int* in_sizes, int n_in,
                              void* d_out, int out_size, void* d_ws, size_t ws_size,
                              hipStream_t stream) {
    const float* z   = (const float*)d_in[0];
    const float* emb = (const float*)d_in[1];

    float* out  = (float*)d_out;
    float* zq   = out;
    float* loss = out + (size_t)BB * CDIM * HW;
    float* idxf = loss + 1;

    char* ws = (char*)d_ws;
    int*            idx_i = (int*)(ws);                      // 131072 B
    float*          enorm = (float*)(ws + 131072);           // 4096 B
    double*         lpart = (double*)(ws + 135168);          // 2048 B
    int*            cnt   = (int*)(ws + 137216);             // 256 B
    int*            list2 = (int*)(ws + 137472);             // 65536 B
    int*            list3 = (int*)(ws + 203008);             // 65536 B
    unsigned short* ehi   = (unsigned short*)(ws + 268544);  // 524288 B

    embcvt_kernel<<<256, 256, 0, stream>>>(emb, ehi);
    enorm_np_kernel<<<KK / 256, 256, 0, stream>>>(emb, enorm, cnt);

    argmin_mfma_kernel<<<NPIX / 64, 256, 0, stream>>>(z, ehi, enorm,
                                                      idx_i, idxf, cnt,
                                                      list2, list3);
    npfix2_kernel<<<256, 256, 0, stream>>>(z, emb, enorm, cnt, list2,
                                           idx_i, idxf);
    npfix3_kernel<<<128, 256, 0, stream>>>(z, emb, enorm, cnt, list3,
                                           idx_i, idxf);

    zq_loss_kernel<<<BB * 8, 256, 0, stream>>>(z, emb, idx_i, zq, lpart);
    loss_fin_kernel<<<1, 64, 0, stream>>>(lpart, loss);
}

// Round 13
// 151.396 us; speedup vs baseline: 1.3732x; 1.2711x over previous
//
#include <hip/hip_runtime.h>

// VQ-VAE vector quantizer, MI355X (gfx950).
// z: [B=32, C=256, H=32, W=32] fp32; emb: [K=1024, C=256] fp32.
// Outputs (flat f32): z_q [B,C,H,W] (8388608) | loss (1) | idx-as-float (32768).
//
// score = ||e||^2 - 2 z.e via ONE bf16 MFMA (A = bf16(-2z) in REGISTERS,
// B = bf16(e) streamed through a 4-deep LDS buffer with counted
// s_waitcnt vmcnt(8) + raw s_barrier pairs — never a full drain mid-loop
// (R12 lesson: __syncthreads' vmcnt(0) drain made the kernel barrier-paced
// at 8% MfmaUtil). enorm is staged to LDS so no global loads pollute the
// vmcnt counting. Top-2 tracked as packed u64 keys; shuffle merge network
// reconstructs per-pixel top-3.
//   gap3 < THR -> list3: full bit-exact numpy-fp32 rescan (~tens of px)
//   gap2 < THR -> list2: np-exact compare of {i1,i2} only  (~1100 px)
// np-winner is within 7e-5 (2x ulp(256)/2) of the exact min; bf16 noise
// sigma ~2.6e-5; THR=2.5e-4 margins proven across R3-R12 runs.

#define BB     32
#define CDIM   256
#define HW     1024
#define KK     1024
#define NPIX   (BB * HW)

#define THR     2.5e-4f
#define LISTCAP 16384
#define FPX     8
#define ENT2    32

typedef __attribute__((ext_vector_type(8))) short bf16x8;
typedef __attribute__((ext_vector_type(4))) float f32x4;
typedef unsigned long long u64;
typedef unsigned int u32;

__device__ __forceinline__ unsigned short bf16_rn(float f) {
    unsigned int u = __float_as_uint(f);
    unsigned int r = u + 0x7fffu + ((u >> 16) & 1u);   // RNE
    return (unsigned short)(r >> 16);
}
__device__ __forceinline__ f32x4 mfma16(bf16x8 a, bf16x8 b, f32x4 c) {
    return __builtin_amdgcn_mfma_f32_16x16x32_bf16(a, b, c, 0, 0, 0);
}
__device__ __forceinline__ u32 ordf(float v) {
    const u32 b = __float_as_uint(v);
    return b ^ ((u32)((int)b >> 31) | 0x80000000u);
}
__device__ __forceinline__ float unordf(u32 u) {
    const u32 b = (u & 0x80000000u) ? (u ^ 0x80000000u) : ~u;
    return __uint_as_float(b);
}
__device__ __forceinline__ u64 min64(u64 a, u64 b) { return a < b ? a : b; }
__device__ __forceinline__ u64 max64(u64 a, u64 b) { return a > b ? a : b; }

// ---------------------------------------------------- numpy pairwise replica
__device__ __forceinline__ float pw128_sq(const float* a) {
#pragma clang fp contract(off)
    float4 u = *(const float4*)(a);
    float4 v = *(const float4*)(a + 4);
    float r0 = u.x * u.x, r1 = u.y * u.y, r2 = u.z * u.z, r3 = u.w * u.w;
    float r4 = v.x * v.x, r5 = v.y * v.y, r6 = v.z * v.z, r7 = v.w * v.w;
    for (int i = 8; i < 128; i += 8) {
        float4 p = *(const float4*)(a + i);
        float4 q = *(const float4*)(a + i + 4);
        float s0 = p.x * p.x; r0 = r0 + s0;
        float s1 = p.y * p.y; r1 = r1 + s1;
        float s2 = p.z * p.z; r2 = r2 + s2;
        float s3 = p.w * p.w; r3 = r3 + s3;
        float s4 = q.x * q.x; r4 = r4 + s4;
        float s5 = q.y * q.y; r5 = r5 + s5;
        float s6 = q.z * q.z; r6 = r6 + s6;
        float s7 = q.w * q.w; r7 = r7 + s7;
    }
    return ((r0 + r1) + (r2 + r3)) + ((r4 + r5) + (r6 + r7));
}

// np einsum SSE replica + final d = fl(fl(znp+en) - fl(2*dot))
__device__ __forceinline__ float np_d_one(const float* __restrict__ er,
                                          const float* zr, float znp_v, float en) {
#pragma clang fp contract(off)
    float l0 = 0.f, l1 = 0.f, l2 = 0.f, l3 = 0.f;
    for (int m = 0; m < 64; ++m) {
        const float4 e4 = *(const float4*)(er + 4 * m);
        const float4 z4 = *(const float4*)(zr + 4 * m);
        float p0 = e4.x * z4.x; l0 = l0 + p0;
        float p1 = e4.y * z4.y; l1 = l1 + p1;
        float p2 = e4.z * z4.z; l2 = l2 + p2;
        float p3 = e4.w * z4.w; l3 = l3 + p3;
    }
    float dot = (l0 + l1) + (l2 + l3);
    float S   = znp_v + en;
    float tw  = 2.0f * dot;
    return S - tw;
}

// ---------------- prep: cnt reset + np-exact e-norms + bf16 swizzled emb
// one thread per code row k; ehi layout (chunk-contiguous fragments):
// off = ((kt*8+ks)*16 + k16)*512 + (lk*16+li)*8 + cj
__global__ __launch_bounds__(256)
void prep_kernel(const float* __restrict__ emb,
                 unsigned short* __restrict__ ehi,
                 float* __restrict__ enorm, int* __restrict__ cnt) {
    const int k = blockIdx.x * 256 + threadIdx.x;   // grid 4 x 256
    if (k == 0) { cnt[0] = 0; cnt[1] = 0; }
    const float* e = emb + (size_t)k * CDIM;
    float s;
    {
#pragma clang fp contract(off)
        float L = pw128_sq(e);
        float R = pw128_sq(e + 128);
        s = L + R;
    }
    enorm[k] = s;
    const int kt = k >> 8, k16 = (k >> 4) & 15, li = k & 15;
#pragma unroll
    for (int c4 = 0; c4 < 64; ++c4) {
        const int c = c4 * 4;
        const float4 v = *(const float4*)(e + c);
        ushort4 hv;
        hv.x = bf16_rn(v.x); hv.y = bf16_rn(v.y);
        hv.z = bf16_rn(v.z); hv.w = bf16_rn(v.w);
        const int ks = c >> 5, lk = (c >> 3) & 3, cj = c & 7;
        const int off = (((kt * 8 + ks) * 16 + k16) << 9) + (lk * 16 + li) * 8 + cj;
        *(ushort4*)(ehi + off) = hv;
    }
}

// ---------------------------------------------------------- MFMA argmin
// block: 64 pixels x all 1024 codes; 4 waves; wave wn owns px wn*16..+15.
// B chunks (16 KB) in 4-deep LDS ring; counted vmcnt, raw barriers.
__global__ __launch_bounds__(256, 2)
void argmin_mfma_kernel(const float* __restrict__ z,
                        const unsigned short* __restrict__ ehi,
                        const float* __restrict__ enorm,
                        int* __restrict__ idx_i, float* __restrict__ idx_f,
                        int* __restrict__ cnt, int* __restrict__ list2,
                        int* __restrict__ list3) {
    __shared__ __align__(16) unsigned short lds[4 * 8192 + 2048]; // 64KB B ring + 4KB enorm
    float* en_lds = (float*)&lds[4 * 8192];

    const int t    = threadIdx.x;
    const int px0  = blockIdx.x * 64;
    const int b    = px0 >> 10;
    const int hw0  = px0 & 1023;
    const int wn   = t >> 6;
    const int lane = t & 63;
    const int li   = lane & 15;
    const int lk   = lane >> 4;

    auto stage = [&](int ch) {
        unsigned short* base = &lds[(ch & 3) * 8192];
#pragma unroll
        for (int p = 0; p < 4; ++p) {
            const int part = wn * 4 + p;                    // 1 KB per part
            const unsigned short* gsl = ehi + (size_t)ch * 8192 + part * 512 + lane * 8;
            __builtin_amdgcn_global_load_lds(
                (const __attribute__((address_space(1))) unsigned int*)(const void*)gsl,
                (__attribute__((address_space(3))) unsigned int*)(void*)(base + part * 512),
                16, 0, 0);
        }
    };

    // enorm -> LDS (so the hot loop issues NO vmcnt-counted loads)
#pragma unroll
    for (int q = 0; q < 4; ++q) en_lds[q * 256 + t] = enorm[q * 256 + t];

    // one-time z staging into ring bufs 0,1 region: [px][c], XOR-swizzled c
#pragma unroll
    for (int it = 0; it < 16; ++it) {
        const int c     = it * 16 + (t >> 4);
        const int chunk = t & 15;
        const f32x4 v = __builtin_nontemporal_load(
            (const f32x4*)(z + ((size_t)(b * 256 + c)) * 1024 + hw0 + chunk * 4));
#pragma unroll
        for (int i = 0; i < 4; ++i) {
            const int ie = (i + chunk) & 3;
            const int px = chunk * 4 + ie;
            lds[px * 256 + (c ^ ((px & 7) << 3))] = bf16_rn(-2.0f * v[ie]);
        }
    }
    __syncthreads();
    // A fragments -> registers (2-way-conflict reads thanks to XOR swizzle)
    bf16x8 Ar[8];
    {
        const int row = wn * 16 + li;
#pragma unroll
        for (int ks = 0; ks < 8; ++ks) {
            const int c0 = (lk * 8 + ks * 32) ^ ((li & 7) << 3);
            Ar[ks] = *(const bf16x8*)&lds[row * 256 + c0];
        }
    }
    __syncthreads();          // all reads of z region done before B overwrite
    stage(0);
    stage(1);

    u64 K1[4], K2[4];
#pragma unroll
    for (int r = 0; r < 4; ++r) { K1[r] = ~0ull; K2[r] = ~0ull; }

    f32x4 acc[16];

#pragma unroll
    for (int ch = 0; ch < 32; ++ch) {        // chunk = kt*8 + ks
        const int kt = ch >> 3;
        const int ks = ch & 7;

        __builtin_amdgcn_s_barrier();        // #1: prev-iter reads complete
        if (ch + 2 < 32) stage(ch + 2);      // ring slot last read 2 iters ago
        if (ch <= 29)      asm volatile("s_waitcnt vmcnt(8)" ::: "memory");
        else if (ch == 30) asm volatile("s_waitcnt vmcnt(4)" ::: "memory");
        else               asm volatile("s_waitcnt vmcnt(0)" ::: "memory");
        __builtin_amdgcn_s_barrier();        // #2: everyone's chunk-ch landed
        __builtin_amdgcn_sched_barrier(0);

        if (ks == 0) {
#pragma unroll
            for (int ni = 0; ni < 16; ++ni) {
                const float en = en_lds[kt * 256 + ni * 16 + li];
                acc[ni][0] = en; acc[ni][1] = en; acc[ni][2] = en; acc[ni][3] = en;
            }
        }

        const unsigned short* bb = &lds[(ch & 3) * 8192];
#pragma unroll
        for (int ni = 0; ni < 16; ++ni) {
            const bf16x8 Bf = *(const bf16x8*)&bb[ni * 512 + lane * 8];
            acc[ni] = mfma16(Ar[ks], Bf, acc[ni]);
        }

        if (ks == 7) {
#pragma unroll
            for (int ni = 0; ni < 16; ++ni) {
                const u32 k = (u32)(kt * 256 + ni * 16 + li);
#pragma unroll
                for (int r = 0; r < 4; ++r) {
                    const u64 key = ((u64)ordf(acc[ni][r]) << 32) | k;
                    const u64 mx  = max64(K1[r], key);
                    K1[r] = min64(K1[r], key);
                    K2[r] = min64(K2[r], mx);
                }
            }
        }
    }

    // cross-lane merge over the 16 li lanes: 3-list merge network
    u64 K3[4];
#pragma unroll
    for (int r = 0; r < 4; ++r) K3[r] = ~0ull;
#pragma unroll
    for (int m = 1; m < 16; m <<= 1) {
#pragma unroll
        for (int r = 0; r < 4; ++r) {
            const u64 b1 = __shfl_xor(K1[r], m, 64);
            const u64 b2 = __shfl_xor(K2[r], m, 64);
            const u64 b3 = __shfl_xor(K3[r], m, 64);
            const u64 m1 = min64(K1[r], b1), M1 = max64(K1[r], b1);
            const u64 m2 = min64(K2[r], b2), M2 = max64(K2[r], b2);
            K1[r] = m1;
            K2[r] = min64(M1, m2);
            K3[r] = min64(max64(M1, m2), min64(M2, min64(K3[r], b3)));
        }
    }
    if (li == 0) {
#pragma unroll
        for (int r = 0; r < 4; ++r) {
            const int n  = px0 + wn * 16 + lk * 4 + r;
            const int i1 = (int)(K1[r] & 0xffffffffu);
            const int i2 = (int)(K2[r] & 0xffffffffu);
            const float v1 = unordf((u32)(K1[r] >> 32));
            const float v2 = unordf((u32)(K2[r] >> 32));
            const float v3 = unordf((u32)(K3[r] >> 32));
            idx_i[n] = i1;
            idx_f[n] = (float)i1;
            if (v3 - v1 < THR) {                  // 3+ candidates: full rescan
                const int slot = atomicAdd(&cnt[1], 1);
                if (slot < LISTCAP) list3[slot] = n;
            } else if (v2 - v1 < THR) {           // exactly 2 candidates
                const int slot = atomicAdd(&cnt[0], 1);
                if (slot < LISTCAP) list2[slot] = n | (i2 << 17);
            }
        }
    }
}

// ---------------- npfix (merged): blocks <256 -> 2-candidate np compare;
//                  blocks >=256 -> full np rescan of list3 pixels
__global__ __launch_bounds__(256)
void npfix_kernel(const float* __restrict__ z, const float* __restrict__ emb,
                  const float* __restrict__ enorm_np,
                  const int* __restrict__ cnt, const int* __restrict__ list2,
                  const int* __restrict__ list3,
                  int* __restrict__ idx_i, float* __restrict__ idx_f) {
    __shared__ __align__(16) float pool[ENT2 * CDIM];    // z rows
    __shared__ float znp_s[ENT2];
    __shared__ int   meta[ENT2 * 2];
    __shared__ float redv[256];
    __shared__ int   redk[256];
    const int t = threadIdx.x;

    if (blockIdx.x < 256) {
        // ---------- list2 path
        const int nflag = min(cnt[0], LISTCAP);
        for (int base = blockIdx.x * ENT2; base < nflag; base += 256 * ENT2) {
            const int nb = min(ENT2, nflag - base);
            if (t < ENT2) {
                const int e = list2[base + (t < nb ? t : nb - 1)];
                meta[t]        = e & 0x1FFFF;
                meta[ENT2 + t] = e >> 17;
            }
            __syncthreads();
            {   // stage z rows: 8 threads per entry
                const int e = t >> 3, part = t & 7;
                const int n = meta[e];
                const float* zb = z + (size_t)(n >> 10) * (CDIM * HW) + (n & 1023);
#pragma unroll
                for (int q = 0; q < 32; ++q) {
                    const int c = part * 32 + q;
                    pool[e * CDIM + c] = zb[(size_t)c * HW];
                }
            }
            __syncthreads();
            if (t < ENT2) {
#pragma clang fp contract(off)
                float L = pw128_sq(&pool[t * CDIM]);
                float R = pw128_sq(&pool[t * CDIM + 128]);
                znp_s[t] = L + R;
            }
            __syncthreads();
            if (t < ENT2 * 2) {
                const int e = t >> 1, cnd = t & 1;
                const int k = cnd ? meta[ENT2 + e] : idx_i[meta[e]];
                redv[t] = np_d_one(emb + (size_t)k * CDIM, &pool[e * CDIM],
                                   znp_s[e], enorm_np[k]);
                redk[t] = k;
            }
            __syncthreads();
            if (t < nb) {
                const float d0 = redv[t * 2], d1 = redv[t * 2 + 1];
                const int   k0 = redk[t * 2], k1 = redk[t * 2 + 1];
                const bool take1 = (d1 < d0) || (d1 == d0 && k1 < k0);
                const int bk = take1 ? k1 : k0;
                const int n = meta[t];
                idx_i[n] = bk;
                idx_f[n] = (float)bk;
            }
            __syncthreads();
        }
    } else {
        // ---------- list3 path (full numpy-exact rescan)
        const int blk = blockIdx.x - 256;            // 64 blocks
        const int nflag = min(cnt[1], LISTCAP);
        for (int base = blk * FPX; base < nflag; base += 64 * FPX) {
            const int npx = min(FPX, nflag - base);
            if (t < FPX) meta[t] = list3[base + (t < npx ? t : npx - 1)];
            __syncthreads();
#pragma unroll
            for (int px = 0; px < FPX; ++px) {
                const int n = meta[px];
                pool[px * CDIM + t] =
                    z[(size_t)(n >> 10) * (CDIM * HW) + (size_t)t * HW + (n & 1023)];
            }
            __syncthreads();
            if (t < FPX) {
#pragma clang fp contract(off)
                float L = pw128_sq(&pool[t * CDIM]);
                float R = pw128_sq(&pool[t * CDIM + 128]);
                znp_s[t] = L + R;
            }
            __syncthreads();

            float bv[FPX]; int bki[FPX];
#pragma unroll
            for (int px = 0; px < FPX; ++px) { bv[px] = 3.4e38f; bki[px] = 0; }

            for (int kj = 0; kj < 4; ++kj) {
                const int k = t + kj * 256;
                const float* er = emb + (size_t)k * CDIM;
                float l[FPX][4];
#pragma unroll
                for (int px = 0; px < FPX; ++px)
#pragma unroll
                    for (int j = 0; j < 4; ++j) l[px][j] = 0.f;
                {
#pragma clang fp contract(off)
                    for (int m = 0; m < 64; ++m) {
                        const float4 e4 = *(const float4*)(er + 4 * m);
#pragma unroll
                        for (int px = 0; px < FPX; ++px) {
                            const float4 z4 = *(const float4*)(&pool[px * CDIM + 4 * m]);
                            float p0 = e4.x * z4.x; l[px][0] = l[px][0] + p0;
                            float p1 = e4.y * z4.y; l[px][1] = l[px][1] + p1;
                            float p2 = e4.z * z4.z; l[px][2] = l[px][2] + p2;
                            float p3 = e4.w * z4.w; l[px][3] = l[px][3] + p3;
                        }
                    }
#pragma unroll
                    for (int px = 0; px < FPX; ++px) {
                        float dot = (l[px][0] + l[px][1]) + (l[px][2] + l[px][3]);
                        float S   = znp_s[px] + enorm_np[k];
                        float tw  = 2.0f * dot;
                        float d   = S - tw;
                        if (d < bv[px]) { bv[px] = d; bki[px] = k; }
                    }
                }
            }
            for (int px = 0; px < FPX; ++px) {
                __syncthreads();
                redv[t] = bv[px]; redk[t] = bki[px];
                __syncthreads();
                for (int s = 128; s > 0; s >>= 1) {
                    if (t < s) {
                        const float v2 = redv[t + s];
                        const int   k2 = redk[t + s];
                        if (v2 < redv[t] || (v2 == redv[t] && k2 < redk[t])) {
                            redv[t] = v2; redk[t] = k2;
                        }
                    }
                    __syncthreads();
                }
                if (t == 0 && px < npx) {
                    const int n = meta[px];
                    idx_i[n] = redk[0];
                    idx_f[n] = (float)redk[0];
                }
            }
            __syncthreads();
        }
    }
}

// ---------------------------------------------------------------- z_q + loss
__global__ __launch_bounds__(256)
void zq_loss_kernel(const float* __restrict__ z, const float* __restrict__ emb,
                    const int* __restrict__ idx_i, float* __restrict__ zq,
                    double* __restrict__ lpart) {
    const int blk = blockIdx.x;
    const int b   = blk >> 3;
    const int cch = blk & 7;
    const int t   = threadIdx.x;
    const int hw  = t * 4;
    const int n0  = b * HW + hw;

    const float* e0 = emb + (size_t)idx_i[n0 + 0] * CDIM + cch * 32;
    const float* e1 = emb + (size_t)idx_i[n0 + 1] * CDIM + cch * 32;
    const float* e2 = emb + (size_t)idx_i[n0 + 2] * CDIM + cch * 32;
    const float* e3 = emb + (size_t)idx_i[n0 + 3] * CDIM + cch * 32;

    const size_t base = ((size_t)b * CDIM + cch * 32) * HW + hw;
    const float* zb = z + base;
    float*       ob = zq + base;

    float ls = 0.f;
#pragma unroll
    for (int c4 = 0; c4 < 8; ++c4) {
        const float4 a0 = *(const float4*)(e0 + 4 * c4);
        const float4 a1 = *(const float4*)(e1 + 4 * c4);
        const float4 a2 = *(const float4*)(e2 + 4 * c4);
        const float4 a3 = *(const float4*)(e3 + 4 * c4);
        const float av0[4] = {a0.x, a0.y, a0.z, a0.w};
        const float av1[4] = {a1.x, a1.y, a1.z, a1.w};
        const float av2[4] = {a2.x, a2.y, a2.z, a2.w};
        const float av3[4] = {a3.x, a3.y, a3.z, a3.w};
#pragma unroll
        for (int cj = 0; cj < 4; ++cj) {
            const size_t off = (size_t)(c4 * 4 + cj) * HW;
            const f32x4 zv = __builtin_nontemporal_load((const f32x4*)(zb + off));
            f32x4 o;
            o[0] = av0[cj]; o[1] = av1[cj]; o[2] = av2[cj]; o[3] = av3[cj];
            __builtin_nontemporal_store(o, (f32x4*)(ob + off));
            const float d0 = o[0] - zv[0], d1 = o[1] - zv[1];
            const float d2 = o[2] - zv[2], d3 = o[3] - zv[3];
            ls += d0 * d0 + d1 * d1 + d2 * d2 + d3 * d3;
        }
    }

    __shared__ float red[256];
    red[t] = ls;
    __syncthreads();
    if (t < 128) red[t] += red[t + 128];
    __syncthreads();
    if (t < 64) {
        float s = red[t] + red[t + 64];
#pragma unroll
        for (int off = 32; off > 0; off >>= 1) s += __shfl_down(s, off, 64);
        if (t == 0) lpart[blk] = (double)s;
    }
}

__global__ void loss_fin_kernel(const double* __restrict__ lpart,
                                float* __restrict__ loss_out) {
    const int t = threadIdx.x;
    double s = 0.0;
#pragma unroll
    for (int i = 0; i < 4; ++i) s += lpart[t * 4 + i];
#pragma unroll
    for (int off = 32; off > 0; off >>= 1) s += __shfl_down(s, off, 64);
    if (t == 0)
        loss_out[0] = (float)(0.25 * s / (double)((size_t)BB * CDIM * HW));
}

// ---------------------------------------------------------------- launch
extern "C" void kernel_launch(void* const* d_in, const int* in_sizes, int n_in,
                              void* d_out, int out_size, void* d_ws, size_t ws_size,
                              hipStream_t stream) {
    const float* z   = (const float*)d_in[0];
    const float* emb = (const float*)d_in[1];

    float* out  = (float*)d_out;
    float* zq   = out;
    float* loss = out + (size_t)BB * CDIM * HW;
    float* idxf = loss + 1;

    char* ws = (char*)d_ws;
    int*            idx_i = (int*)(ws);                      // 131072 B
    float*          enorm = (float*)(ws + 131072);           // 4096 B
    double*         lpart = (double*)(ws + 135168);          // 2048 B
    int*            cnt   = (int*)(ws + 137216);             // 256 B
    int*            list2 = (int*)(ws + 137472);             // 65536 B
    int*            list3 = (int*)(ws + 203008);             // 65536 B
    unsigned short* ehi   = (unsigned short*)(ws + 268544);  // 524288 B

    prep_kernel<<<KK / 256, 256, 0, stream>>>(emb, ehi, enorm, cnt);

    argmin_mfma_kernel<<<NPIX / 64, 256, 0, stream>>>(z, ehi, enorm,
                                                      idx_i, idxf, cnt,
                                                      list2, list3);
    npfix_kernel<<<320, 256, 0, stream>>>(z, emb, enorm, cnt, list2, list3,
                                          idx_i, idxf);

    zq_loss_kernel<<<BB * 8, 256, 0, stream>>>(z, emb, idx_i, zq, lpart);
    loss_fin_kernel<<<1, 64, 0, stream>>>(lpart, loss);
}